// Round 1
// baseline (620.333 us; speedup 1.0000x reference)
//
#include <hip/hip_runtime.h>
#include <hip/hip_bf16.h>

typedef __bf16 bf16x8 __attribute__((ext_vector_type(8)));
typedef float f32x4 __attribute__((ext_vector_type(4)));
typedef unsigned short us8 __attribute__((ext_vector_type(8)));
typedef unsigned short us4 __attribute__((ext_vector_type(4)));

__device__ inline float bf2f(unsigned short u) {
  union { unsigned u; float f; } x; x.u = ((unsigned)u) << 16; return x.f;
}
__device__ inline unsigned short f2bf(float f) {
  union { float f; unsigned u; } x; x.f = f;
  unsigned r = x.u + 0x7fffu + ((x.u >> 16) & 1u);  // RNE
  return (unsigned short)(r >> 16);
}

// f32 -> bf16 cast, 4 elems/thread
__global__ __launch_bounds__(256) void cast_f32_bf16(
    const float* __restrict__ src, unsigned short* __restrict__ dst, int n4) {
  int i = blockIdx.x * 256 + threadIdx.x;
  if (i >= n4) return;
  float4 f = ((const float4*)src)[i];
  us4 u;
  u[0] = f2bf(f.x); u[1] = f2bf(f.y); u[2] = f2bf(f.z); u[3] = f2bf(f.w);
  *(us4*)&dst[i * 4] = u;
}

#define GLLDS(g, l) __builtin_amdgcn_global_load_lds( \
    (const __attribute__((address_space(1))) void*)(g), \
    (__attribute__((address_space(3))) void*)(l), 16, 0, 0)

// C[M,N] = A[M,K] * B[N,K]^T  (+epilogue), all bf16 (ushort storage), f32 accum.
// EPI: 0 = v*p1 -> bf16        (C row-major, ldc)
//      1 = v + bias[col]       (C row-major, ldc)
//      2 = relu(v + bias[col]) (C row-major, ldc)
//      3 = v + bias[col], store TRANSPOSED: C[col*ldc + row], ldc = M
// Requires M%128==0, N%128==0, K%32==0.
template<int EPI>
__global__ __launch_bounds__(256)
void gemm_bt(const unsigned short* __restrict__ A,
             const unsigned short* __restrict__ B,
             const float* __restrict__ bias, float p1,
             unsigned short* __restrict__ C,
             int M, int N, int K, int ldc) {
  __shared__ unsigned short lds[2][2][4096];  // [buf][A/B][128*32]
  const int tid = threadIdx.x;
  const int wave = tid >> 6, lane = tid & 63;
  const int wm = wave >> 1, wn = wave & 1;
  const long m0 = (long)blockIdx.y * 128, n0 = (long)blockIdx.x * 128;

  f32x4 acc[4][4];
#pragma unroll
  for (int i = 0; i < 4; ++i)
#pragma unroll
    for (int j = 0; j < 4; ++j) acc[i][j] = (f32x4){0.f, 0.f, 0.f, 0.f};

  const int srow = tid >> 2;        // 0..63
  const int scol = (tid & 3) * 8;   // 0,8,16,24

  // prologue: stage k0=0 into buf 0
#pragma unroll
  for (int j = 0; j < 2; ++j) {
    const unsigned short* ga = A + (m0 + j * 64 + srow) * K + scol;
    const unsigned short* gb = B + (n0 + j * 64 + srow) * K + scol;
    GLLDS(ga, &lds[0][0][j * 2048 + wave * 512]);
    GLLDS(gb, &lds[0][1][j * 2048 + wave * 512]);
  }

  const int lr = lane & 15;
  const int lk = (lane >> 4) * 8;
  const int KT = K >> 5;
  int cur = 0;
  for (int kt = 0; kt < KT; ++kt) {
    __syncthreads();  // drains vmcnt (staged tile ready) + protects re-stage
    if (kt + 1 < KT) {
      const int k0 = (kt + 1) << 5;
#pragma unroll
      for (int j = 0; j < 2; ++j) {
        const unsigned short* ga = A + (m0 + j * 64 + srow) * K + k0 + scol;
        const unsigned short* gb = B + (n0 + j * 64 + srow) * K + k0 + scol;
        GLLDS(ga, &lds[cur ^ 1][0][j * 2048 + wave * 512]);
        GLLDS(gb, &lds[cur ^ 1][1][j * 2048 + wave * 512]);
      }
    }
    bf16x8 af[4], bfr[4];
#pragma unroll
    for (int i = 0; i < 4; ++i)
      af[i] = *(const bf16x8*)&lds[cur][0][(wm * 64 + i * 16 + lr) * 32 + lk];
#pragma unroll
    for (int j = 0; j < 4; ++j)
      bfr[j] = *(const bf16x8*)&lds[cur][1][(wn * 64 + j * 16 + lr) * 32 + lk];
#pragma unroll
    for (int i = 0; i < 4; ++i)
#pragma unroll
      for (int j = 0; j < 4; ++j)
        acc[i][j] = __builtin_amdgcn_mfma_f32_16x16x32_bf16(af[i], bfr[j], acc[i][j], 0, 0, 0);
    cur ^= 1;
  }

  // epilogue: C/D layout col=lane&15, row=(lane>>4)*4+reg  [m89/m91]
  const int cc = lane & 15, cr = (lane >> 4) * 4;
#pragma unroll
  for (int i = 0; i < 4; ++i) {
#pragma unroll
    for (int j = 0; j < 4; ++j) {
      const long grow = m0 + wm * 64 + i * 16 + cr;
      const long gcol = n0 + wn * 64 + j * 16 + cc;
      f32x4 v = acc[i][j];
      if constexpr (EPI == 0) {
#pragma unroll
        for (int r = 0; r < 4; ++r)
          C[(grow + r) * (long)ldc + gcol] = f2bf(v[r] * p1);
      } else if constexpr (EPI == 1 || EPI == 2) {
        const float b = bias[gcol];
#pragma unroll
        for (int r = 0; r < 4; ++r) {
          float t = v[r] + b;
          if constexpr (EPI == 2) t = fmaxf(t, 0.f);
          C[(grow + r) * (long)ldc + gcol] = f2bf(t);
        }
      } else {  // EPI == 3
        const float b = bias[gcol];
        us4 pk;
#pragma unroll
        for (int r = 0; r < 4; ++r) pk[r] = f2bf(v[r] + b);
        *(us4*)&C[gcol * (long)ldc + grow] = pk;
      }
    }
  }
}

// row-wise softmax over N=8192 bf16, in place. One block (256 thr) per row.
__global__ __launch_bounds__(256) void softmax_rows(unsigned short* __restrict__ S, int N) {
  const int tid = threadIdx.x, lane = tid & 63, wave = tid >> 6;
  unsigned short* p = S + (size_t)blockIdx.x * N;
  float v[32];
  float mx = -3.0e38f;
#pragma unroll
  for (int k = 0; k < 4; ++k) {
    us8 u = *(const us8*)&p[(tid + k * 256) * 8];
#pragma unroll
    for (int r = 0; r < 8; ++r) { float f = bf2f(u[r]); v[k * 8 + r] = f; mx = fmaxf(mx, f); }
  }
#pragma unroll
  for (int o = 32; o; o >>= 1) mx = fmaxf(mx, __shfl_xor(mx, o));
  __shared__ float rm[4], rs[4];
  if (lane == 0) rm[wave] = mx;
  __syncthreads();
  mx = fmaxf(fmaxf(rm[0], rm[1]), fmaxf(rm[2], rm[3]));
  float s = 0.f;
#pragma unroll
  for (int e = 0; e < 32; ++e) { float ev = __expf(v[e] - mx); v[e] = ev; s += ev; }
#pragma unroll
  for (int o = 32; o; o >>= 1) s += __shfl_xor(s, o);
  if (lane == 0) rs[wave] = s;
  __syncthreads();
  s = rs[0] + rs[1] + rs[2] + rs[3];
  const float inv = 1.0f / s;
#pragma unroll
  for (int k = 0; k < 4; ++k) {
    us8 u;
#pragma unroll
    for (int r = 0; r < 8; ++r) u[r] = f2bf(v[k * 8 + r] * inv);
    *(us8*)&p[(tid + k * 256) * 8] = u;
  }
}

// out[row] = H[row,:] . w   (D=1024), one wave per row
__global__ __launch_bounds__(256) void final_dot(const unsigned short* __restrict__ H,
                                                 const float* __restrict__ w,
                                                 float* __restrict__ out) {
  const int lane = threadIdx.x & 63, wave = threadIdx.x >> 6;
  const int row = blockIdx.x * 4 + wave;
  const unsigned short* h = H + (size_t)row * 1024;
  float s = 0.f;
#pragma unroll
  for (int k = 0; k < 2; ++k) {
    const int base = (lane + k * 64) * 8;
    us8 u = *(const us8*)&h[base];
#pragma unroll
    for (int r = 0; r < 8; ++r) s += bf2f(u[r]) * w[base + r];
  }
#pragma unroll
  for (int o = 32; o; o >>= 1) s += __shfl_xor(s, o);
  if (lane == 0) out[row] = s;
}

extern "C" void kernel_launch(void* const* d_in, const int* in_sizes, int n_in,
                              void* d_out, int out_size, void* d_ws, size_t ws_size,
                              hipStream_t stream) {
  const float* x  = (const float*)d_in[0];
  const float* Wq = (const float*)d_in[1];
  const float* bq = (const float*)d_in[2];
  const float* Wk = (const float*)d_in[3];
  const float* bk = (const float*)d_in[4];
  const float* Wv = (const float*)d_in[5];
  const float* bv = (const float*)d_in[6];
  const float* W1 = (const float*)d_in[7];
  const float* b1 = (const float*)d_in[8];
  const float* W2 = (const float*)d_in[9];
  const float* b2 = (const float*)d_in[10];
  const float* W3 = (const float*)d_in[11];
  const float* b3 = (const float*)d_in[12];
  const float* fw = (const float*)d_in[13];
  float* out = (float*)d_out;

  const int N = 8192, D = 1024;
  char* ws = (char*)d_ws;
  unsigned short* Sb  = (unsigned short*)ws;                       // 128 MB
  unsigned short* xb  = (unsigned short*)(ws + (size_t)N * N * 2); // 16 MB
  unsigned short* Qb  = xb + (size_t)N * D;
  unsigned short* Kb  = Qb + (size_t)N * D;
  unsigned short* Vt  = Kb + (size_t)N * D;                        // [D, N] transposed V
  unsigned short* Wqb = Vt + (size_t)N * D;
  unsigned short* Wkb = Wqb + (size_t)D * D;
  unsigned short* Wvb = Wkb + (size_t)D * D;
  unsigned short* W1b = Wvb + (size_t)D * D;
  unsigned short* W2b = W1b + (size_t)D * D;
  unsigned short* W3b = W2b + (size_t)D * D;
  // reuse (dead buffers):
  unsigned short* att = xb;   // attended [N, D]
  unsigned short* H1  = Qb;
  unsigned short* H2  = Kb;
  unsigned short* H3  = Vt;

  // ---- casts to bf16 ----
  cast_f32_bf16<<<(N * D / 4 + 255) / 256, 256, 0, stream>>>(x, xb, N * D / 4);
  cast_f32_bf16<<<(D * D / 4 + 255) / 256, 256, 0, stream>>>(Wq, Wqb, D * D / 4);
  cast_f32_bf16<<<(D * D / 4 + 255) / 256, 256, 0, stream>>>(Wk, Wkb, D * D / 4);
  cast_f32_bf16<<<(D * D / 4 + 255) / 256, 256, 0, stream>>>(Wv, Wvb, D * D / 4);
  cast_f32_bf16<<<(D * D / 4 + 255) / 256, 256, 0, stream>>>(W1, W1b, D * D / 4);
  cast_f32_bf16<<<(D * D / 4 + 255) / 256, 256, 0, stream>>>(W2, W2b, D * D / 4);
  cast_f32_bf16<<<(D * D / 4 + 255) / 256, 256, 0, stream>>>(W3, W3b, D * D / 4);

  const dim3 blk(256);
  // ---- QKV projections ----
  gemm_bt<1><<<dim3(D / 128, N / 128), blk, 0, stream>>>(xb, Wqb, bq, 0.f, Qb, N, D, D, D);
  gemm_bt<1><<<dim3(D / 128, N / 128), blk, 0, stream>>>(xb, Wkb, bk, 0.f, Kb, N, D, D, D);
  gemm_bt<3><<<dim3(D / 128, N / 128), blk, 0, stream>>>(xb, Wvb, bv, 0.f, Vt, N, D, D, N);
  // ---- S = Q K^T * scale ----
  gemm_bt<0><<<dim3(N / 128, N / 128), blk, 0, stream>>>(Qb, Kb, nullptr, 0.03125f, Sb, N, N, D, N);
  // ---- softmax rows (in place) ----
  softmax_rows<<<N, 256, 0, stream>>>(Sb, N);
  // ---- attended = P V  (B = Vt [D,N]) ----
  gemm_bt<0><<<dim3(D / 128, N / 128), blk, 0, stream>>>(Sb, Vt, nullptr, 1.0f, att, N, D, N, D);
  // ---- MLP ----
  gemm_bt<2><<<dim3(D / 128, N / 128), blk, 0, stream>>>(att, W1b, b1, 0.f, H1, N, D, D, D);
  gemm_bt<2><<<dim3(D / 128, N / 128), blk, 0, stream>>>(H1, W2b, b2, 0.f, H2, N, D, D, D);
  gemm_bt<2><<<dim3(D / 128, N / 128), blk, 0, stream>>>(H2, W3b, b3, 0.f, H3, N, D, D, D);
  // ---- final projection to [N] ----
  final_dot<<<N / 4, 256, 0, stream>>>(H3, fw, out);
}

// Round 2
// 529.506 us; speedup vs baseline: 1.1715x; 1.1715x over previous
//
#include <hip/hip_runtime.h>
#include <hip/hip_bf16.h>

typedef __bf16 bf16x8 __attribute__((ext_vector_type(8)));
typedef float f32x4 __attribute__((ext_vector_type(4)));
typedef unsigned short us8 __attribute__((ext_vector_type(8)));
typedef unsigned short us4 __attribute__((ext_vector_type(4)));

__device__ inline float bf2f(unsigned short u) {
  union { unsigned u; float f; } x; x.u = ((unsigned)u) << 16; return x.f;
}
__device__ inline unsigned short f2bf(float f) {
  union { float f; unsigned u; } x; x.f = f;
  unsigned r = x.u + 0x7fffu + ((x.u >> 16) & 1u);  // RNE
  return (unsigned short)(r >> 16);
}

// Bijective chunked-XCD swizzle (m204): HW dispatches block b round-robin to
// XCD b%8; give XCD x a CONTIGUOUS chunk of work ids so same-A-panel blocks
// share one L2.
__device__ inline unsigned xcd_chunk(unsigned b, unsigned nwg) {
  const unsigned x = b & 7u, idx = b >> 3;
  const unsigned q = nwg >> 3, r = nwg & 7u;
  const unsigned base = (x < r) ? x * (q + 1u) : r * (q + 1u) + (x - r) * q;
  return base + idx;
}

// f32 -> bf16 cast, 4 elems/thread
__global__ __launch_bounds__(256) void cast_f32_bf16(
    const float* __restrict__ src, unsigned short* __restrict__ dst, int n4) {
  int i = blockIdx.x * 256 + threadIdx.x;
  if (i >= n4) return;
  float4 f = ((const float4*)src)[i];
  us4 u;
  u[0] = f2bf(f.x); u[1] = f2bf(f.y); u[2] = f2bf(f.z); u[3] = f2bf(f.w);
  *(us4*)&dst[i * 4] = u;
}

#define GLLDS(g, l) __builtin_amdgcn_global_load_lds( \
    (const __attribute__((address_space(1))) void*)(g), \
    (__attribute__((address_space(3))) void*)(l), 16, 0, 0)

// C[M,N] = A[M,K] * B[N,K]^T  (+epilogue), all bf16 (ushort storage), f32 accum.
// EPI: 0 = v*p1 -> bf16        (C row-major, ldc)
//      1 = v + bias[col]       (C row-major, ldc)
//      2 = relu(v + bias[col]) (C row-major, ldc)
//      3 = v + bias[col], store TRANSPOSED: C[col*ldc + row], ldc = M
// Requires M%128==0, N%128==0, K%32==0.
template<int EPI>
__global__ __launch_bounds__(256)
void gemm_bt(const unsigned short* __restrict__ A,
             const unsigned short* __restrict__ B,
             const float* __restrict__ bias, float p1,
             unsigned short* __restrict__ C,
             int M, int N, int K, int ldc) {
  __shared__ unsigned short lds[2][2][4096];  // [buf][A/B][128*32]
  const int tid = threadIdx.x;
  const int wave = tid >> 6, lane = tid & 63;
  const int wm = wave >> 1, wn = wave & 1;

  // chunked-XCD block swizzle; col index fastest so same-A-panel blocks are
  // consecutive work ids -> same XCD L2.
  const unsigned gx = gridDim.x, nwg = gx * gridDim.y;
  const unsigned w = xcd_chunk(blockIdx.y * gx + blockIdx.x, nwg);
  const long m0 = (long)(w / gx) * 128, n0 = (long)(w % gx) * 128;

  f32x4 acc[4][4];
#pragma unroll
  for (int i = 0; i < 4; ++i)
#pragma unroll
    for (int j = 0; j < 4; ++j) acc[i][j] = (f32x4){0.f, 0.f, 0.f, 0.f};

  const int srow = tid >> 2;        // 0..63
  const int scol = (tid & 3) * 8;   // 0,8,16,24

  // prologue: stage k0=0 into buf 0
#pragma unroll
  for (int j = 0; j < 2; ++j) {
    const unsigned short* ga = A + (m0 + j * 64 + srow) * K + scol;
    const unsigned short* gb = B + (n0 + j * 64 + srow) * K + scol;
    GLLDS(ga, &lds[0][0][j * 2048 + wave * 512]);
    GLLDS(gb, &lds[0][1][j * 2048 + wave * 512]);
  }

  const int lr = lane & 15;
  const int lk = (lane >> 4) * 8;
  const int KT = K >> 5;
  int cur = 0;
  for (int kt = 0; kt < KT; ++kt) {
    __syncthreads();  // drains vmcnt (staged tile ready) + protects re-stage
    if (kt + 1 < KT) {
      const int k0 = (kt + 1) << 5;
#pragma unroll
      for (int j = 0; j < 2; ++j) {
        const unsigned short* ga = A + (m0 + j * 64 + srow) * K + k0 + scol;
        const unsigned short* gb = B + (n0 + j * 64 + srow) * K + k0 + scol;
        GLLDS(ga, &lds[cur ^ 1][0][j * 2048 + wave * 512]);
        GLLDS(gb, &lds[cur ^ 1][1][j * 2048 + wave * 512]);
      }
    }
    bf16x8 af[4], bfr[4];
#pragma unroll
    for (int i = 0; i < 4; ++i)
      af[i] = *(const bf16x8*)&lds[cur][0][(wm * 64 + i * 16 + lr) * 32 + lk];
#pragma unroll
    for (int j = 0; j < 4; ++j)
      bfr[j] = *(const bf16x8*)&lds[cur][1][(wn * 64 + j * 16 + lr) * 32 + lk];
#pragma unroll
    for (int i = 0; i < 4; ++i)
#pragma unroll
      for (int j = 0; j < 4; ++j)
        acc[i][j] = __builtin_amdgcn_mfma_f32_16x16x32_bf16(af[i], bfr[j], acc[i][j], 0, 0, 0);
    cur ^= 1;
  }

  // epilogue: C/D layout col=lane&15, row=(lane>>4)*4+reg  [m89/m91]
  const int cc = lane & 15, cr = (lane >> 4) * 4;
#pragma unroll
  for (int i = 0; i < 4; ++i) {
#pragma unroll
    for (int j = 0; j < 4; ++j) {
      const long grow = m0 + wm * 64 + i * 16 + cr;
      const long gcol = n0 + wn * 64 + j * 16 + cc;
      f32x4 v = acc[i][j];
      if constexpr (EPI == 0) {
#pragma unroll
        for (int r = 0; r < 4; ++r)
          C[(grow + r) * (long)ldc + gcol] = f2bf(v[r] * p1);
      } else if constexpr (EPI == 1 || EPI == 2) {
        const float b = bias[gcol];
#pragma unroll
        for (int r = 0; r < 4; ++r) {
          float t = v[r] + b;
          if constexpr (EPI == 2) t = fmaxf(t, 0.f);
          C[(grow + r) * (long)ldc + gcol] = f2bf(t);
        }
      } else {  // EPI == 3
        const float b = bias[gcol];
        us4 pk;
#pragma unroll
        for (int r = 0; r < 4; ++r) pk[r] = f2bf(v[r] + b);
        *(us4*)&C[gcol * (long)ldc + grow] = pk;
      }
    }
  }
}

// row-wise softmax over N=8192 bf16, in place. One block (256 thr) per row.
__global__ __launch_bounds__(256) void softmax_rows(unsigned short* __restrict__ S, int N) {
  const int tid = threadIdx.x, lane = tid & 63, wave = tid >> 6;
  unsigned short* p = S + (size_t)blockIdx.x * N;
  float v[32];
  float mx = -3.0e38f;
#pragma unroll
  for (int k = 0; k < 4; ++k) {
    us8 u = *(const us8*)&p[(tid + k * 256) * 8];
#pragma unroll
    for (int r = 0; r < 8; ++r) { float f = bf2f(u[r]); v[k * 8 + r] = f; mx = fmaxf(mx, f); }
  }
#pragma unroll
  for (int o = 32; o; o >>= 1) mx = fmaxf(mx, __shfl_xor(mx, o));
  __shared__ float rm[4], rs[4];
  if (lane == 0) rm[wave] = mx;
  __syncthreads();
  mx = fmaxf(fmaxf(rm[0], rm[1]), fmaxf(rm[2], rm[3]));
  float s = 0.f;
#pragma unroll
  for (int e = 0; e < 32; ++e) { float ev = __expf(v[e] - mx); v[e] = ev; s += ev; }
#pragma unroll
  for (int o = 32; o; o >>= 1) s += __shfl_xor(s, o);
  if (lane == 0) rs[wave] = s;
  __syncthreads();
  s = rs[0] + rs[1] + rs[2] + rs[3];
  const float inv = 1.0f / s;
#pragma unroll
  for (int k = 0; k < 4; ++k) {
    us8 u;
#pragma unroll
    for (int r = 0; r < 8; ++r) u[r] = f2bf(v[k * 8 + r] * inv);
    *(us8*)&p[(tid + k * 256) * 8] = u;
  }
}

// out[row] = H[row,:] . w   (D=1024), one wave per row
__global__ __launch_bounds__(256) void final_dot(const unsigned short* __restrict__ H,
                                                 const float* __restrict__ w,
                                                 float* __restrict__ out) {
  const int lane = threadIdx.x & 63, wave = threadIdx.x >> 6;
  const int row = blockIdx.x * 4 + wave;
  const unsigned short* h = H + (size_t)row * 1024;
  float s = 0.f;
#pragma unroll
  for (int k = 0; k < 2; ++k) {
    const int base = (lane + k * 64) * 8;
    us8 u = *(const us8*)&h[base];
#pragma unroll
    for (int r = 0; r < 8; ++r) s += bf2f(u[r]) * w[base + r];
  }
#pragma unroll
  for (int o = 32; o; o >>= 1) s += __shfl_xor(s, o);
  if (lane == 0) out[row] = s;
}

extern "C" void kernel_launch(void* const* d_in, const int* in_sizes, int n_in,
                              void* d_out, int out_size, void* d_ws, size_t ws_size,
                              hipStream_t stream) {
  const float* x  = (const float*)d_in[0];
  const float* Wq = (const float*)d_in[1];
  const float* bq = (const float*)d_in[2];
  const float* Wk = (const float*)d_in[3];
  const float* bk = (const float*)d_in[4];
  const float* Wv = (const float*)d_in[5];
  const float* bv = (const float*)d_in[6];
  const float* W1 = (const float*)d_in[7];
  const float* b1 = (const float*)d_in[8];
  const float* W2 = (const float*)d_in[9];
  const float* b2 = (const float*)d_in[10];
  const float* W3 = (const float*)d_in[11];
  const float* b3 = (const float*)d_in[12];
  const float* fw = (const float*)d_in[13];
  float* out = (float*)d_out;

  const int N = 8192, D = 1024;
  char* ws = (char*)d_ws;
  unsigned short* Sb  = (unsigned short*)ws;                       // 128 MB
  unsigned short* xb  = (unsigned short*)(ws + (size_t)N * N * 2); // 16 MB
  unsigned short* Qb  = xb + (size_t)N * D;
  unsigned short* Kb  = Qb + (size_t)N * D;
  unsigned short* Vt  = Kb + (size_t)N * D;                        // [D, N] transposed V
  unsigned short* Wqb = Vt + (size_t)N * D;
  unsigned short* Wkb = Wqb + (size_t)D * D;
  unsigned short* Wvb = Wkb + (size_t)D * D;
  unsigned short* W1b = Wvb + (size_t)D * D;
  unsigned short* W2b = W1b + (size_t)D * D;
  unsigned short* W3b = W2b + (size_t)D * D;
  // reuse (dead buffers):
  unsigned short* att = xb;   // attended [N, D]
  unsigned short* H1  = Qb;
  unsigned short* H2  = Kb;
  unsigned short* H3  = Vt;

  // ---- casts to bf16 ----
  cast_f32_bf16<<<(N * D / 4 + 255) / 256, 256, 0, stream>>>(x, xb, N * D / 4);
  cast_f32_bf16<<<(D * D / 4 + 255) / 256, 256, 0, stream>>>(Wq, Wqb, D * D / 4);
  cast_f32_bf16<<<(D * D / 4 + 255) / 256, 256, 0, stream>>>(Wk, Wkb, D * D / 4);
  cast_f32_bf16<<<(D * D / 4 + 255) / 256, 256, 0, stream>>>(Wv, Wvb, D * D / 4);
  cast_f32_bf16<<<(D * D / 4 + 255) / 256, 256, 0, stream>>>(W1, W1b, D * D / 4);
  cast_f32_bf16<<<(D * D / 4 + 255) / 256, 256, 0, stream>>>(W2, W2b, D * D / 4);
  cast_f32_bf16<<<(D * D / 4 + 255) / 256, 256, 0, stream>>>(W3, W3b, D * D / 4);

  const dim3 blk(256);
  // ---- QKV projections ----
  gemm_bt<1><<<dim3(D / 128, N / 128), blk, 0, stream>>>(xb, Wqb, bq, 0.f, Qb, N, D, D, D);
  gemm_bt<1><<<dim3(D / 128, N / 128), blk, 0, stream>>>(xb, Wkb, bk, 0.f, Kb, N, D, D, D);
  gemm_bt<3><<<dim3(D / 128, N / 128), blk, 0, stream>>>(xb, Wvb, bv, 0.f, Vt, N, D, D, N);
  // ---- S = Q K^T * scale ----
  gemm_bt<0><<<dim3(N / 128, N / 128), blk, 0, stream>>>(Qb, Kb, nullptr, 0.03125f, Sb, N, N, D, N);
  // ---- softmax rows (in place) ----
  softmax_rows<<<N, 256, 0, stream>>>(Sb, N);
  // ---- attended = P V  (B = Vt [D,N]) ----
  gemm_bt<0><<<dim3(D / 128, N / 128), blk, 0, stream>>>(Sb, Vt, nullptr, 1.0f, att, N, D, N, D);
  // ---- MLP ----
  gemm_bt<2><<<dim3(D / 128, N / 128), blk, 0, stream>>>(att, W1b, b1, 0.f, H1, N, D, D, D);
  gemm_bt<2><<<dim3(D / 128, N / 128), blk, 0, stream>>>(H1, W2b, b2, 0.f, H2, N, D, D, D);
  gemm_bt<2><<<dim3(D / 128, N / 128), blk, 0, stream>>>(H2, W3b, b3, 0.f, H3, N, D, D, D);
  // ---- final projection to [N] ----
  final_dot<<<N / 4, 256, 0, stream>>>(H3, fw, out);
}

// Round 3
// 487.292 us; speedup vs baseline: 1.2730x; 1.0866x over previous
//
#include <hip/hip_runtime.h>
#include <hip/hip_bf16.h>

typedef __bf16 bf16x8 __attribute__((ext_vector_type(8)));
typedef float f32x4 __attribute__((ext_vector_type(4)));
typedef unsigned short us8 __attribute__((ext_vector_type(8)));
typedef unsigned short us4 __attribute__((ext_vector_type(4)));

__device__ inline float bf2f(unsigned short u) {
  union { unsigned u; float f; } x; x.u = ((unsigned)u) << 16; return x.f;
}
__device__ inline unsigned short f2bf(float f) {
  union { float f; unsigned u; } x; x.f = f;
  unsigned r = x.u + 0x7fffu + ((x.u >> 16) & 1u);  // RNE
  return (unsigned short)(r >> 16);
}

// Bijective chunked-XCD swizzle (m204).
__device__ inline unsigned xcd_chunk(unsigned b, unsigned nwg) {
  const unsigned x = b & 7u, idx = b >> 3;
  const unsigned q = nwg >> 3, r = nwg & 7u;
  const unsigned base = (x < r) ? x * (q + 1u) : r * (q + 1u) + (x - r) * q;
  return base + idx;
}

__global__ __launch_bounds__(256) void cast_f32_bf16(
    const float* __restrict__ src, unsigned short* __restrict__ dst, int n4) {
  int i = blockIdx.x * 256 + threadIdx.x;
  if (i >= n4) return;
  float4 f = ((const float4*)src)[i];
  us4 u;
  u[0] = f2bf(f.x); u[1] = f2bf(f.y); u[2] = f2bf(f.z); u[3] = f2bf(f.w);
  *(us4*)&dst[i * 4] = u;
}

#define GLLDS(g, l) __builtin_amdgcn_global_load_lds( \
    (const __attribute__((address_space(1))) void*)(g), \
    (__attribute__((address_space(3))) void*)(l), 16, 0, 0)
#define VMCNT4 asm volatile("s_waitcnt vmcnt(4)" ::: "memory")
#define LGKM0  asm volatile("s_waitcnt lgkmcnt(0)" ::: "memory")
#define BAR    __builtin_amdgcn_s_barrier()
#define SCHED0 __builtin_amdgcn_sched_barrier(0)

// ---------------- 256x256 8-phase GEMM (T2+T3+T4+T5) ----------------
// C[M,N] = A[M,K]*B[N,K]^T * scale -> bf16. M%256==0, N%256==0, K%64==0.
// 512 thr = 8 waves (2M x 4N). Per-wave out: rows {wm*64+[0,64), 128+wm*64+[0,64)},
// cols {wn*32+[0,32), 128+wn*32+[0,32)} -> phase (mh,nh) touches only A-half mh,
// B-half nh. LDS 128 KiB, XOR swizzle chunk^=(row&7) both sides.
__global__ __launch_bounds__(512, 2)
void gemm256_bt(const unsigned short* __restrict__ A,
                const unsigned short* __restrict__ B,
                float scale, unsigned short* __restrict__ C,
                int M, int N, int K, int ldc) {
  __shared__ unsigned short ldsA[2][16384];  // [buf][half(8192)+row*64+chunk*8]
  __shared__ unsigned short ldsB[2][16384];
  const int tid = threadIdx.x, wave = tid >> 6, lane = tid & 63;
  const int wm = wave >> 2, wn = wave & 3;
  const unsigned gx = gridDim.x, nwg = gx * gridDim.y;
  const unsigned w = xcd_chunk(blockIdx.y * gx + blockIdx.x, nwg);
  const long m0 = (long)(w / gx) * 256, n0 = (long)(w % gx) * 256;

  f32x4 acc[8][4];
#pragma unroll
  for (int i = 0; i < 8; ++i)
#pragma unroll
    for (int j = 0; j < 4; ++j) acc[i][j] = (f32x4){0.f, 0.f, 0.f, 0.f};

  // staging geometry: thread t, sub-round j in {0,1}: LDS 16B-slot (j*512+t)
  // = row j*64 + (t>>3), chunk t&7. Inverse-swizzled global source chunk.
  const int srow = tid >> 3;                  // 0..63
  const int scol = ((tid & 7) ^ (srow & 7)) * 8;

  auto stageA = [&](int buf, int h, long kb) {
#pragma unroll
    for (int j = 0; j < 2; ++j) {
      const unsigned short* g = A + (m0 + h * 128 + j * 64 + srow) * (long)K + kb + scol;
      GLLDS(g, &ldsA[buf][h * 8192 + j * 4096 + wave * 512]);
    }
  };
  auto stageB = [&](int buf, int h, long kb) {
#pragma unroll
    for (int j = 0; j < 2; ++j) {
      const unsigned short* g = B + (n0 + h * 128 + j * 64 + srow) * (long)K + kb + scol;
      GLLDS(g, &ldsB[buf][h * 8192 + j * 4096 + wave * 512]);
    }
  };

  const int lr = lane & 15, l7 = lane & 7, lk = lane >> 4;
  bf16x8 a[4][2], b0[2][2], b1[2][2];
  auto readA = [&](int buf, int h) {
#pragma unroll
    for (int f = 0; f < 4; ++f) {
      const int rh = wm * 64 + f * 16 + lr;
#pragma unroll
      for (int kh = 0; kh < 2; ++kh)
        a[f][kh] = *(const bf16x8*)&ldsA[buf][h * 8192 + rh * 64 + (((kh * 4 + lk) ^ l7) * 8)];
    }
  };
  auto readB = [&](int buf, int nh, bf16x8 (&b)[2][2]) {
#pragma unroll
    for (int g2 = 0; g2 < 2; ++g2) {
      const int rh = wn * 32 + g2 * 16 + lr;
#pragma unroll
      for (int kh = 0; kh < 2; ++kh)
        b[g2][kh] = *(const bf16x8*)&ldsB[buf][nh * 8192 + rh * 64 + (((kh * 4 + lk) ^ l7) * 8)];
    }
  };

  // prologue: tile 0 in stage order A0,B0,B1,A1 (first-use compatible gating)
  stageA(0, 0, 0); stageB(0, 0, 0); stageB(0, 1, 0); stageA(0, 1, 0);

  const int KT = K >> 6;
  for (int kt = 0; kt < KT; ++kt) {
    const int cur = kt & 1, nxt = cur ^ 1;
    const long kn = (long)(kt + 1) << 6;
    const bool more = (kt + 1 < KT);
    // boundary gate: A0,B0 of tile kt landed (B1,A1 may be in flight)
    VMCNT4; BAR; SCHED0;
    // ---- phase 0: (mh0,nh0) ----
    readA(cur, 0); readB(cur, 0, b0);
    if (more) stageA(nxt, 0, kn);
    BAR; LGKM0; SCHED0;
    __builtin_amdgcn_s_setprio(1);
#pragma unroll
    for (int f = 0; f < 4; ++f)
#pragma unroll
      for (int g = 0; g < 2; ++g)
#pragma unroll
        for (int kh = 0; kh < 2; ++kh)
          acc[f][g] = __builtin_amdgcn_mfma_f32_16x16x32_bf16(a[f][kh], b0[g][kh], acc[f][g], 0, 0, 0);
    __builtin_amdgcn_s_setprio(0);
    VMCNT4;  // B1 of tile kt landed
    BAR; SCHED0;
    // ---- phase 1: (mh0,nh1) ----
    readB(cur, 1, b1);
    if (more) stageB(nxt, 0, kn);
    BAR; LGKM0; SCHED0;
    __builtin_amdgcn_s_setprio(1);
#pragma unroll
    for (int f = 0; f < 4; ++f)
#pragma unroll
      for (int g = 0; g < 2; ++g)
#pragma unroll
        for (int kh = 0; kh < 2; ++kh)
          acc[f][2 + g] = __builtin_amdgcn_mfma_f32_16x16x32_bf16(a[f][kh], b1[g][kh], acc[f][2 + g], 0, 0, 0);
    __builtin_amdgcn_s_setprio(0);
    VMCNT4;  // A1 of tile kt landed
    BAR; SCHED0;
    // ---- phase 2: (mh1,nh1) ----
    readA(cur, 1);
    if (more) stageB(nxt, 1, kn);
    BAR; LGKM0; SCHED0;
    __builtin_amdgcn_s_setprio(1);
#pragma unroll
    for (int f = 0; f < 4; ++f)
#pragma unroll
      for (int g = 0; g < 2; ++g)
#pragma unroll
        for (int kh = 0; kh < 2; ++kh)
          acc[4 + f][2 + g] = __builtin_amdgcn_mfma_f32_16x16x32_bf16(a[f][kh], b1[g][kh], acc[4 + f][2 + g], 0, 0, 0);
    __builtin_amdgcn_s_setprio(0);
    BAR; SCHED0;
    // ---- phase 3: (mh1,nh0) — no new ds_reads ----
    if (more) stageA(nxt, 1, kn);
    BAR; SCHED0;
    __builtin_amdgcn_s_setprio(1);
#pragma unroll
    for (int f = 0; f < 4; ++f)
#pragma unroll
      for (int g = 0; g < 2; ++g)
#pragma unroll
        for (int kh = 0; kh < 2; ++kh)
          acc[4 + f][g] = __builtin_amdgcn_mfma_f32_16x16x32_bf16(a[f][kh], b0[g][kh], acc[4 + f][g], 0, 0, 0);
    __builtin_amdgcn_s_setprio(0);
  }

  // epilogue
  const int cc = lane & 15, cr = (lane >> 4) * 4;
#pragma unroll
  for (int m = 0; m < 8; ++m) {
#pragma unroll
    for (int g = 0; g < 4; ++g) {
      const long grow = m0 + (m >> 2) * 128 + wm * 64 + (m & 3) * 16 + cr;
      const long gcol = n0 + (g >> 1) * 128 + wn * 32 + (g & 1) * 16 + cc;
      const f32x4 v = acc[m][g];
#pragma unroll
      for (int r = 0; r < 4; ++r)
        C[(grow + r) * (long)ldc + gcol] = f2bf(v[r] * scale);
    }
  }
}

// ---------------- 128x128 m97-structure GEMM (proven) ----------------
template<int EPI>
__global__ __launch_bounds__(256)
void gemm_bt(const unsigned short* __restrict__ A,
             const unsigned short* __restrict__ B,
             const float* __restrict__ bias, float p1,
             unsigned short* __restrict__ C,
             int M, int N, int K, int ldc) {
  __shared__ unsigned short lds[2][2][4096];
  const int tid = threadIdx.x;
  const int wave = tid >> 6, lane = tid & 63;
  const int wm = wave >> 1, wn = wave & 1;
  const unsigned gx = gridDim.x, nwg = gx * gridDim.y;
  const unsigned w = xcd_chunk(blockIdx.y * gx + blockIdx.x, nwg);
  const long m0 = (long)(w / gx) * 128, n0 = (long)(w % gx) * 128;

  f32x4 acc[4][4];
#pragma unroll
  for (int i = 0; i < 4; ++i)
#pragma unroll
    for (int j = 0; j < 4; ++j) acc[i][j] = (f32x4){0.f, 0.f, 0.f, 0.f};

  const int srow = tid >> 2;
  const int scol = (tid & 3) * 8;
#pragma unroll
  for (int j = 0; j < 2; ++j) {
    const unsigned short* ga = A + (m0 + j * 64 + srow) * K + scol;
    const unsigned short* gb = B + (n0 + j * 64 + srow) * K + scol;
    GLLDS(ga, &lds[0][0][j * 2048 + wave * 512]);
    GLLDS(gb, &lds[0][1][j * 2048 + wave * 512]);
  }

  const int lr = lane & 15;
  const int lk = (lane >> 4) * 8;
  const int KT = K >> 5;
  int cur = 0;
  for (int kt = 0; kt < KT; ++kt) {
    __syncthreads();
    if (kt + 1 < KT) {
      const int k0 = (kt + 1) << 5;
#pragma unroll
      for (int j = 0; j < 2; ++j) {
        const unsigned short* ga = A + (m0 + j * 64 + srow) * K + k0 + scol;
        const unsigned short* gb = B + (n0 + j * 64 + srow) * K + k0 + scol;
        GLLDS(ga, &lds[cur ^ 1][0][j * 2048 + wave * 512]);
        GLLDS(gb, &lds[cur ^ 1][1][j * 2048 + wave * 512]);
      }
    }
    bf16x8 af[4], bfr[4];
#pragma unroll
    for (int i = 0; i < 4; ++i)
      af[i] = *(const bf16x8*)&lds[cur][0][(wm * 64 + i * 16 + lr) * 32 + lk];
#pragma unroll
    for (int j = 0; j < 4; ++j)
      bfr[j] = *(const bf16x8*)&lds[cur][1][(wn * 64 + j * 16 + lr) * 32 + lk];
#pragma unroll
    for (int i = 0; i < 4; ++i)
#pragma unroll
      for (int j = 0; j < 4; ++j)
        acc[i][j] = __builtin_amdgcn_mfma_f32_16x16x32_bf16(af[i], bfr[j], acc[i][j], 0, 0, 0);
    cur ^= 1;
  }

  const int cc = lane & 15, cr = (lane >> 4) * 4;
#pragma unroll
  for (int i = 0; i < 4; ++i) {
#pragma unroll
    for (int j = 0; j < 4; ++j) {
      const long grow = m0 + wm * 64 + i * 16 + cr;
      const long gcol = n0 + wn * 64 + j * 16 + cc;
      f32x4 v = acc[i][j];
      if constexpr (EPI == 0) {
#pragma unroll
        for (int r = 0; r < 4; ++r)
          C[(grow + r) * (long)ldc + gcol] = f2bf(v[r] * p1);
      } else if constexpr (EPI == 1 || EPI == 2) {
        const float b = bias[gcol];
#pragma unroll
        for (int r = 0; r < 4; ++r) {
          float t = v[r] + b;
          if constexpr (EPI == 2) t = fmaxf(t, 0.f);
          C[(grow + r) * (long)ldc + gcol] = f2bf(t);
        }
      } else {
        const float b = bias[gcol];
        us4 pk;
#pragma unroll
        for (int r = 0; r < 4; ++r) pk[r] = f2bf(v[r] + b);
        *(us4*)&C[gcol * (long)ldc + grow] = pk;
      }
    }
  }
}

__global__ __launch_bounds__(256) void softmax_rows(unsigned short* __restrict__ S, int N) {
  const int tid = threadIdx.x, lane = tid & 63, wave = tid >> 6;
  unsigned short* p = S + (size_t)blockIdx.x * N;
  float v[32];
  float mx = -3.0e38f;
#pragma unroll
  for (int k = 0; k < 4; ++k) {
    us8 u = *(const us8*)&p[(tid + k * 256) * 8];
#pragma unroll
    for (int r = 0; r < 8; ++r) { float f = bf2f(u[r]); v[k * 8 + r] = f; mx = fmaxf(mx, f); }
  }
#pragma unroll
  for (int o = 32; o; o >>= 1) mx = fmaxf(mx, __shfl_xor(mx, o));
  __shared__ float rm[4], rs[4];
  if (lane == 0) rm[wave] = mx;
  __syncthreads();
  mx = fmaxf(fmaxf(rm[0], rm[1]), fmaxf(rm[2], rm[3]));
  float s = 0.f;
#pragma unroll
  for (int e = 0; e < 32; ++e) { float ev = __expf(v[e] - mx); v[e] = ev; s += ev; }
#pragma unroll
  for (int o = 32; o; o >>= 1) s += __shfl_xor(s, o);
  if (lane == 0) rs[wave] = s;
  __syncthreads();
  s = rs[0] + rs[1] + rs[2] + rs[3];
  const float inv = 1.0f / s;
#pragma unroll
  for (int k = 0; k < 4; ++k) {
    us8 u;
#pragma unroll
    for (int r = 0; r < 8; ++r) u[r] = f2bf(v[k * 8 + r] * inv);
    *(us8*)&p[(tid + k * 256) * 8] = u;
  }
}

__global__ __launch_bounds__(256) void final_dot(const unsigned short* __restrict__ H,
                                                 const float* __restrict__ w,
                                                 float* __restrict__ out) {
  const int lane = threadIdx.x & 63, wave = threadIdx.x >> 6;
  const int row = blockIdx.x * 4 + wave;
  const unsigned short* h = H + (size_t)row * 1024;
  float s = 0.f;
#pragma unroll
  for (int k = 0; k < 2; ++k) {
    const int base = (lane + k * 64) * 8;
    us8 u = *(const us8*)&h[base];
#pragma unroll
    for (int r = 0; r < 8; ++r) s += bf2f(u[r]) * w[base + r];
  }
#pragma unroll
  for (int o = 32; o; o >>= 1) s += __shfl_xor(s, o);
  if (lane == 0) out[row] = s;
}

extern "C" void kernel_launch(void* const* d_in, const int* in_sizes, int n_in,
                              void* d_out, int out_size, void* d_ws, size_t ws_size,
                              hipStream_t stream) {
  const float* x  = (const float*)d_in[0];
  const float* Wq = (const float*)d_in[1];
  const float* bq = (const float*)d_in[2];
  const float* Wk = (const float*)d_in[3];
  const float* bk = (const float*)d_in[4];
  const float* Wv = (const float*)d_in[5];
  const float* bv = (const float*)d_in[6];
  const float* W1 = (const float*)d_in[7];
  const float* b1 = (const float*)d_in[8];
  const float* W2 = (const float*)d_in[9];
  const float* b2 = (const float*)d_in[10];
  const float* W3 = (const float*)d_in[11];
  const float* b3 = (const float*)d_in[12];
  const float* fw = (const float*)d_in[13];
  float* out = (float*)d_out;

  const int N = 8192, D = 1024;
  char* ws = (char*)d_ws;
  unsigned short* Sb  = (unsigned short*)ws;                       // 128 MB
  unsigned short* xb  = (unsigned short*)(ws + (size_t)N * N * 2);
  unsigned short* Qb  = xb + (size_t)N * D;
  unsigned short* Kb  = Qb + (size_t)N * D;
  unsigned short* Vt  = Kb + (size_t)N * D;                        // [D, N]
  unsigned short* Wqb = Vt + (size_t)N * D;
  unsigned short* Wkb = Wqb + (size_t)D * D;
  unsigned short* Wvb = Wkb + (size_t)D * D;
  unsigned short* W1b = Wvb + (size_t)D * D;
  unsigned short* W2b = W1b + (size_t)D * D;
  unsigned short* W3b = W2b + (size_t)D * D;
  unsigned short* att = xb;
  unsigned short* H1  = Qb;
  unsigned short* H2  = Kb;
  unsigned short* H3  = Vt;

  cast_f32_bf16<<<(N * D / 4 + 255) / 256, 256, 0, stream>>>(x, xb, N * D / 4);
  cast_f32_bf16<<<(D * D / 4 + 255) / 256, 256, 0, stream>>>(Wq, Wqb, D * D / 4);
  cast_f32_bf16<<<(D * D / 4 + 255) / 256, 256, 0, stream>>>(Wk, Wkb, D * D / 4);
  cast_f32_bf16<<<(D * D / 4 + 255) / 256, 256, 0, stream>>>(Wv, Wvb, D * D / 4);
  cast_f32_bf16<<<(D * D / 4 + 255) / 256, 256, 0, stream>>>(W1, W1b, D * D / 4);
  cast_f32_bf16<<<(D * D / 4 + 255) / 256, 256, 0, stream>>>(W2, W2b, D * D / 4);
  cast_f32_bf16<<<(D * D / 4 + 255) / 256, 256, 0, stream>>>(W3, W3b, D * D / 4);

  const dim3 blk(256);
  gemm_bt<1><<<dim3(D / 128, N / 128), blk, 0, stream>>>(xb, Wqb, bq, 0.f, Qb, N, D, D, D);
  gemm_bt<1><<<dim3(D / 128, N / 128), blk, 0, stream>>>(xb, Wkb, bk, 0.f, Kb, N, D, D, D);
  gemm_bt<3><<<dim3(D / 128, N / 128), blk, 0, stream>>>(xb, Wvb, bv, 0.f, Vt, N, D, D, N);
  // ---- S = Q K^T * scale : 256² 8-phase kernel ----
  gemm256_bt<<<dim3(N / 256, N / 256), dim3(512), 0, stream>>>(Qb, Kb, 0.03125f, Sb, N, N, D, N);
  softmax_rows<<<N, 256, 0, stream>>>(Sb, N);
  gemm_bt<0><<<dim3(D / 128, N / 128), blk, 0, stream>>>(Sb, Vt, nullptr, 1.0f, att, N, D, N, D);
  gemm_bt<2><<<dim3(D / 128, N / 128), blk, 0, stream>>>(att, W1b, b1, 0.f, H1, N, D, D, D);
  gemm_bt<2><<<dim3(D / 128, N / 128), blk, 0, stream>>>(H1, W2b, b2, 0.f, H2, N, D, D, D);
  gemm_bt<2><<<dim3(D / 128, N / 128), blk, 0, stream>>>(H2, W3b, b3, 0.f, H3, N, D, D, D);
  final_dot<<<N / 4, 256, 0, stream>>>(H3, fw, out);
}